// Round 4
// baseline (259.388 us; speedup 1.0000x reference)
//
#include <hip/hip_runtime.h>

#define KS 11
#define TBX 32
#define TBY 32
#define SLOTS 32        // row ring: slot = absolute_row & 31
#define HST 35          // odd stride spreads H-write banks
#define IMG 512
#define OUT_H 502
#define OUT_W 502
#define N_IMG 64
#define GXD 16
#define GYD 16
#define NBLK (GXD * GYD * N_IMG)
#define MSTRIDE (SLOTS * HST)   // 1120 floats per map

__global__ __launch_bounds__(256, 8) void ssim_main(
    const float* __restrict__ g_a, const float* __restrict__ g_b,
    const float* __restrict__ g_w, float* __restrict__ bsum)
{
  __shared__ float s_h[5 * MSTRIDE];   // 22,400 B
  __shared__ float s_red[4];

  const int t = threadIdx.x;
  const int x0 = blockIdx.x * TBX, y0 = blockIdx.y * TBY;
  const float* __restrict__ A = g_a + (size_t)blockIdx.z * (IMG * IMG);
  const float* __restrict__ B = g_b + (size_t)blockIdx.z * (IMG * IMG);
  const bool edge = (x0 == IMG - TBX) || (y0 == IMG - TBX);

  // exact rank-1 factor of the Gaussian window: w[i][j] = u[i]*u[j]
  float u[KS];
  {
    const float inv = 1.0f / sqrtf(g_w[5 * KS + 5]);
#pragma unroll
    for (int j = 0; j < KS; ++j) u[j] = g_w[j * KS + 5] * inv;
  }

  // ---- horizontal task: one row (r_abs), one 4-col strip (k) ----
  auto htask = [&](int r_abs, int k) {
    const int c0 = 4 * k;
    const int slot = r_abs & (SLOTS - 1);
    const int gy = y0 + r_abs;
    const int gxs = x0 + c0;          // multiple of 4 -> 16B aligned

    float ea[14], eb[14];
    if (!edge) {
      const float* pa = A + gy * IMG + gxs;
      const float* pb = B + gy * IMG + gxs;
      *(float4*)&ea[0] = *(const float4*)(pa);
      *(float4*)&ea[4] = *(const float4*)(pa + 4);
      *(float4*)&ea[8] = *(const float4*)(pa + 8);
      *(float2*)&ea[12] = *(const float2*)(pa + 12);
      *(float4*)&eb[0] = *(const float4*)(pb);
      *(float4*)&eb[4] = *(const float4*)(pb + 4);
      *(float4*)&eb[8] = *(const float4*)(pb + 8);
      *(float2*)&eb[12] = *(const float2*)(pb + 12);
    } else {
      const int gyc = min(gy, IMG - 1);
      const float* pa = A + gyc * IMG;
      const float* pb = B + gyc * IMG;
#pragma unroll
      for (int i = 0; i < 14; ++i) {
        const int gx = min(gxs + i, IMG - 1);
        ea[i] = pa[gx];
        eb[i] = pb[gx];
      }
    }

    float* dst = &s_h[slot * HST + c0];
#pragma unroll
    for (int cc = 0; cc < 4; ++cc) {
      float m1 = 0.f, m2 = 0.f, q11 = 0.f, q22 = 0.f, q12 = 0.f;
#pragma unroll
      for (int j = 0; j < KS; ++j) {
        const float a = ea[cc + j], b = eb[cc + j];
        const float ta = u[j] * a, tb = u[j] * b;
        m1 += ta;
        m2 += tb;
        q11 = fmaf(ta, a, q11);
        q22 = fmaf(tb, b, q22);
        q12 = fmaf(ta, b, q12);
      }
      dst[0 * MSTRIDE + cc] = m1;
      dst[1 * MSTRIDE + cc] = m2;
      dst[2 * MSTRIDE + cc] = q11;
      dst[3 * MSTRIDE + cc] = q22;
      dst[4 * MSTRIDE + cc] = q12;
    }
  };

  // ---- vertical task: 2 consecutive y at one x; returns partial score ----
  auto vtask = [&](int ybase_phase) -> float {
    const int x = t & 31;
    const int yb = ybase_phase + 2 * (t >> 5);
    int addr[12];
#pragma unroll
    for (int k = 0; k < 12; ++k)
      addr[k] = ((yb + k) & (SLOTS - 1)) * HST + x;

    float o[5][2];
#pragma unroll
    for (int m = 0; m < 5; ++m) {
      const float* base = &s_h[m * MSTRIDE];
      float v[12];
#pragma unroll
      for (int k = 0; k < 12; ++k) v[k] = base[addr[k]];
      float a0 = 0.f, a1 = 0.f;
#pragma unroll
      for (int i = 0; i < KS; ++i) {
        a0 = fmaf(u[i], v[i], a0);
        a1 = fmaf(u[i], v[i + 1], a1);
      }
      o[m][0] = a0;
      o[m][1] = a1;
    }

    float sc = 0.f;
    const int gx_ = x0 + x;
#pragma unroll
    for (int yy = 0; yy < 2; ++yy) {
      const int gy_ = y0 + yb + yy;
      if (gx_ < OUT_W && gy_ < OUT_H) {
        const float C1 = 1e-4f, C2 = 9e-4f;
        const float mu1 = o[0][yy], mu2 = o[1][yy];
        const float mu1s = mu1 * mu1, mu2s = mu2 * mu2, m12 = mu1 * mu2;
        const float sig1 = o[2][yy] - mu1s, sig2 = o[3][yy] - mu2s,
                    sig12 = o[4][yy] - m12;
        sc += ((2.f * m12 + C1) * (2.f * sig12 + C2)) /
              ((mu1s + mu2s + C1) * (sig1 + sig2 + C2));
      }
    }
    return sc;
  };

  // ---- phase A: rows 0..25 -> V y 0..15 ; phase B: rows 26..41 -> y 16..31
  if (t < 208) htask(t >> 3, t & 7);
  __syncthreads();
  float score = vtask(0);
  __syncthreads();                    // V-A reads slots 0..25 must finish
  if (t < 128) htask(26 + (t >> 3), t & 7);   // writes slots 26..31, 0..9
  __syncthreads();
  score += vtask(16);

  // ---- block reduction -> bsum[bid] ----
#pragma unroll
  for (int off = 32; off > 0; off >>= 1)
    score += __shfl_down(score, off);
  const int wave = t >> 6, lane = t & 63;
  if (lane == 0) s_red[wave] = score;
  __syncthreads();
  if (t == 0) {
    const int bid = (int)((blockIdx.z * GYD + blockIdx.y) * GXD + blockIdx.x);
    bsum[bid] = s_red[0] + s_red[1] + s_red[2] + s_red[3];
  }
}

__global__ __launch_bounds__(256) void ssim_final(
    const float* __restrict__ bsum, float* __restrict__ out)
{
  // 16384 floats = 16 independent float4 loads per thread (pipelined)
  const float4* b4 = (const float4*)bsum;
  double v = 0.0;
#pragma unroll
  for (int k = 0; k < 16; ++k) {
    const float4 f = b4[k * 256 + threadIdx.x];
    v += (double)((f.x + f.y) + (f.z + f.w));
  }
#pragma unroll
  for (int off = 32; off > 0; off >>= 1)
    v += __shfl_down(v, off);
  __shared__ double s_red[4];
  const int wave = (int)threadIdx.x >> 6, lane = (int)threadIdx.x & 63;
  if (lane == 0) s_red[wave] = v;
  __syncthreads();
  if (threadIdx.x == 0) {
    const double total = s_red[0] + s_red[1] + s_red[2] + s_red[3];
    out[0] = (float)(total / (double)((size_t)N_IMG * OUT_H * OUT_W));
  }
}

extern "C" void kernel_launch(void* const* d_in, const int* in_sizes, int n_in,
                              void* d_out, int out_size, void* d_ws, size_t ws_size,
                              hipStream_t stream) {
  const float* yh = (const float*)d_in[0];
  const float* yy = (const float*)d_in[1];
  const float* w  = (const float*)d_in[2];
  float* bsum = (float*)d_ws;          // NBLK floats = 64 KB
  float* out = (float*)d_out;

  dim3 grid(GXD, GYD, N_IMG);
  hipLaunchKernelGGL(ssim_main, grid, dim3(256), 0, stream, yh, yy, w, bsum);
  hipLaunchKernelGGL(ssim_final, dim3(1), dim3(256), 0, stream, bsum, out);
}